// Round 7
// baseline (95.520 us; speedup 1.0000x reference)
//
#include <hip/hip_runtime.h>
#include <hip/hip_bf16.h>

#define D 32
#define FACTOR (-1.0f / 128.0f)   // -1/(2*8^2)
#define LOG2E  1.44269504088896340736f

typedef __attribute__((ext_vector_type(8)))  short bf16x8;
typedef __attribute__((ext_vector_type(16))) float f32x16;
typedef __attribute__((ext_vector_type(4)))  float f32x4;

#if __has_builtin(__builtin_amdgcn_exp2f)
#define EXP2(x) __builtin_amdgcn_exp2f(x)
#else
#define EXP2(x) exp2f(x)
#endif

__device__ __forceinline__ ushort bfr(float x) {
    __hip_bfloat16 h = __float2bfloat16(x);     // RNE
    return *reinterpret_cast<ushort*>(&h);
}
__device__ __forceinline__ float bf2f(ushort u) {
    uint w = ((uint)u) << 16;
    return *reinterpret_cast<float*>(&w);
}
__device__ __forceinline__ uint pk2(float a, float b) {
    return (uint)bfr(a) | ((uint)bfr(b) << 16);
}

// ---------------------------------------------------------------------------
// Prep: bf16 copies of X and Y, transposed yT[d][m], and y2s[m] =
// (FACTOR*LOG2E) * ||y~_m||^2 (pre-scaled; the x^2 term cancels in nom/den
// and is dropped entirely). 4 lanes per row, 8 elements per lane.
// ---------------------------------------------------------------------------
__global__ __launch_bounds__(256) void msk_prep(const float* __restrict__ X,
                                                const float* __restrict__ Y,
                                                ushort* __restrict__ Xb,
                                                ushort* __restrict__ Yb,
                                                ushort* __restrict__ yT,
                                                float* __restrict__ y2s,
                                                int N, int M) {
    const int t = blockIdx.x * 256 + threadIdx.x;
    const int i = t >> 2;
    const int c = t & 3;
    if (i >= N + M) return;
    const bool isX = (i < N);
    const int r = isX ? i : i - N;
    const float* src = (isX ? X : Y) + (size_t)r * D + c * 8;

    float4 va = *reinterpret_cast<const float4*>(src);
    float4 vb = *reinterpret_cast<const float4*>(src + 4);
    float f[8] = {va.x, va.y, va.z, va.w, vb.x, vb.y, vb.z, vb.w};

    ushort u[8];
    float s = 0.f;
#pragma unroll
    for (int k = 0; k < 8; ++k) {
        u[k] = bfr(f[k]);
        float g = bf2f(u[k]);
        s = fmaf(g, g, s);
    }
    s += __shfl_xor(s, 1);
    s += __shfl_xor(s, 2);

    uint w[4];
#pragma unroll
    for (int q = 0; q < 4; ++q) w[q] = (uint)u[2 * q] | ((uint)u[2 * q + 1] << 16);

    ushort* dstrow = (isX ? Xb : Yb) + (size_t)r * D + c * 8;
    *reinterpret_cast<uint4*>(dstrow) = *reinterpret_cast<const uint4*>(w);

    if (!isX) {
        if (c == 0) y2s[r] = s * (FACTOR * LOG2E);
#pragma unroll
        for (int k = 0; k < 8; ++k)
            yT[(size_t)(c * 8 + k) * M + r] = u[k];
    }
}

// ---------------------------------------------------------------------------
// Main fused kernel. Block = 4 waves x 32 n = 128 n sharing the m-stream.
// Per 128-m step (ONE barrier): cooperative coalesced loads of Yb (128x64B)
// and yT (32x256B) into double-buffered XOR-swizzled LDS; per wave 4 tiles
// of {GEMM1 2x mfma_32x32x16 -> exp2(fma) -> pack -> GEMM2 2x mfma}.
// k' = exp2(dot*C2 + y2s[m]) — the per-n x^2 factor cancels in nom/den.
// ---------------------------------------------------------------------------
__global__ __launch_bounds__(256) void msk_main(const ushort* __restrict__ Xb,
                                                const ushort* __restrict__ Yb,
                                                const ushort* __restrict__ yT,
                                                const float* __restrict__ y2s,
                                                float* __restrict__ pnom,
                                                float* __restrict__ pden,
                                                int N, int M, int chunk) {
    __shared__ uint4 lYb[2][128][4];   // [buf][m-row][16B slot], slot c at c^(r&3)
    __shared__ uint4 lYT[2][32][16];   // [buf][d-row][16B slot], slot s at s^(d&7)

    const int tid  = threadIdx.x;
    const int lane = tid & 63;
    const int wid  = tid >> 6;
    const int h    = lane >> 5;
    const int ln   = lane & 31;
    const int n0   = blockIdx.x * 128 + wid * 32;
    const int m0b  = blockIdx.y * chunk;
    const int ns   = chunk >> 7;                 // 128-m steps

    const int rY = tid >> 2, cY = tid & 3;       // Yb tile: m-row (x2), 16B col
    const int dT = tid >> 3, sT = tid & 7;       // yT tile: d-row, 16B col (x2)

    // x B-fragments: element (h,j) <-> d = 16*ks + 8h + j
    const ushort* xrow = Xb + (size_t)(n0 + ln) * D + h * 8;
    const bf16x8 xf0 = *reinterpret_cast<const bf16x8*>(xrow);
    const bf16x8 xf1 = *reinterpret_cast<const bf16x8*>(xrow + 16);

    const float C2 = -2.0f * (FACTOR * LOG2E);

    f32x16 nom = {};
    float den0 = 0.f, den1 = 0.f;
    union Fu { uint u[4]; bf16x8 v; };

    uint4 ldY0, ldY1, ldT0, ldT1;
    auto issue_loads = [&](int step) {
        const int m = m0b + step * 128;
        ldY0 = (reinterpret_cast<const uint4*>(Yb + (size_t)(m + rY) * D))[cY];
        ldY1 = (reinterpret_cast<const uint4*>(Yb + (size_t)(m + rY + 64) * D))[cY];
        const uint4* tp = reinterpret_cast<const uint4*>(yT + (size_t)dT * M + m);
        ldT0 = tp[sT];
        ldT1 = tp[sT + 8];
    };
    auto stage = [&](int bb) {
        lYb[bb][rY][cY ^ (rY & 3)]       = ldY0;
        lYb[bb][rY + 64][cY ^ (rY & 3)]  = ldY1;       // (rY+64)&3 == rY&3
        lYT[bb][dT][sT ^ (dT & 7)]       = ldT0;
        lYT[bb][dT][(sT + 8) ^ (dT & 7)] = ldT1;       // +8 commutes with low-3 XOR
    };

    issue_loads(0);
    stage(0);
    if (ns > 1) issue_loads(1);
    __syncthreads();

    for (int t = 0; t < ns; ++t) {
        const int b  = t & 1;
        const int m0 = m0b + t * 128;

        if (t + 1 < ns) {
            stage((t + 1) & 1);                  // buf_next last read before prev barrier
            if (t + 2 < ns) issue_loads(t + 2);  // latency hidden under this step's compute
        }

        const int sw = ln & 7;
        const uint2* yr = reinterpret_cast<const uint2*>(&lYT[b][ln][0]);

#pragma unroll
        for (int tA = 0; tA < 4; ++tA) {
            // GEMM1 A-frags from LDS Yb rows tA*32+ln
            const int lr = tA * 32 + ln;
            const bf16x8 af0 = *reinterpret_cast<const bf16x8*>(&lYb[b][lr][(0 + h) ^ (ln & 3)]);
            const bf16x8 af1 = *reinterpret_cast<const bf16x8*>(&lYb[b][lr][(2 + h) ^ (ln & 3)]);

            f32x16 s = {};
            s = __builtin_amdgcn_mfma_f32_32x32x16_bf16(af0, xf0, s, 0, 0, 0);
            s = __builtin_amdgcn_mfma_f32_32x32x16_bf16(af1, xf1, s, 0, 0, 0);
            // s reg r: m = m0 + tA*32 + (r&3) + 8*(r>>2) + 4h ; n = n0 + ln

            const int mt = m0 + tA * 32;
            Fu pa0, pa1;
#pragma unroll
            for (int r4 = 0; r4 < 4; ++r4) {
                f32x4 yv = *reinterpret_cast<const f32x4*>(y2s + mt + r4 * 8 + h * 4);
                float kq[4];
#pragma unroll
                for (int q = 0; q < 4; ++q)
                    kq[q] = EXP2(fmaf(s[r4 * 4 + q], C2, yv[q]));
                den0 += kq[0] + kq[1];
                den1 += kq[2] + kq[3];
                uint w0 = pk2(kq[0], kq[1]);
                uint w1 = pk2(kq[2], kq[3]);
                if (r4 < 2) { pa0.u[r4 * 2] = w0; pa0.u[r4 * 2 + 1] = w1; }
                else        { pa1.u[(r4 - 2) * 2] = w0; pa1.u[(r4 - 2) * 2 + 1] = w1; }
            }

            // GEMM2 B-frags from LDS yT row ln; logical slot q = tA*4 + 2ks + j2
            Fu b0, b1;
            *reinterpret_cast<uint2*>(&b0.u[0]) = yr[((tA * 4 + 0) ^ sw) * 2 + h];
            *reinterpret_cast<uint2*>(&b0.u[2]) = yr[((tA * 4 + 1) ^ sw) * 2 + h];
            *reinterpret_cast<uint2*>(&b1.u[0]) = yr[((tA * 4 + 2) ^ sw) * 2 + h];
            *reinterpret_cast<uint2*>(&b1.u[2]) = yr[((tA * 4 + 3) ^ sw) * 2 + h];

            nom = __builtin_amdgcn_mfma_f32_32x32x16_bf16(pa0.v, b0.v, nom, 0, 0, 0);
            nom = __builtin_amdgcn_mfma_f32_32x32x16_bf16(pa1.v, b1.v, nom, 0, 0, 0);
        }

        __syncthreads();
    }

    // den: halves hold disjoint m partials for the same n=ln
    float den = den0 + den1;
    den += __shfl_xor(den, 32);

    const size_t base = (size_t)blockIdx.y * N;
#pragma unroll
    for (int r = 0; r < 16; ++r) {
        const int row = (r & 3) + 8 * (r >> 2) + 4 * h;      // n offset
        pnom[(base + n0 + row) * 32 + ln] = nom[r];          // d = ln
    }
    if (h == 0) pden[base + n0 + ln] = den;
}

// ---------------------------------------------------------------------------
// Reduce over m-chunks and divide.
// ---------------------------------------------------------------------------
__global__ __launch_bounds__(256) void msk_reduce(const float* __restrict__ pnom,
                                                  const float* __restrict__ pden,
                                                  float* __restrict__ out,
                                                  int N, int S) {
    const int t = blockIdx.x * blockDim.x + threadIdx.x;
    if (t >= N * 32) return;
    const int n = t >> 5;
    float nom = 0.f, den = 0.f;
    for (int s = 0; s < S; ++s) {
        nom += pnom[(size_t)s * N * 32 + t];
        den += pden[(size_t)s * N + n];
    }
    out[t] = nom / den;
}

// ---------------------------------------------------------------------------
extern "C" void kernel_launch(void* const* d_in, const int* in_sizes, int n_in,
                              void* d_out, int out_size, void* d_ws, size_t ws_size,
                              hipStream_t stream) {
    const float* X = (const float*)d_in[0];
    const float* Y = (const float*)d_in[1];
    float* out     = (float*)d_out;

    const int N = in_sizes[0] / D;   // 8192
    const int M = in_sizes[1] / D;   // 8192

    char* p = (char*)d_ws;
    ushort* Xb  = (ushort*)p; p += (size_t)N * D * sizeof(ushort);
    ushort* Yb  = (ushort*)p; p += (size_t)M * D * sizeof(ushort);
    ushort* yT  = (ushort*)p; p += (size_t)M * D * sizeof(ushort);
    float*  y2s = (float*)p;  p += (size_t)M * sizeof(float);
    size_t used = (size_t)(p - (char*)d_ws);
    used = (used + 255) & ~(size_t)255;

    const size_t per_s = (size_t)N * 33 * sizeof(float);
    int S = 16;                                  // 1024 blocks = 4/CU
    while (S > 1 && used + (size_t)S * per_s > ws_size) S >>= 1;
    const int chunk = M / S;                     // 512 -> 4 steps of 128 m

    float* pnom = (float*)((char*)d_ws + used);
    float* pden = pnom + (size_t)S * N * 32;

    msk_prep<<<dim3(((N + M) * 4 + 255) / 256), dim3(256), 0, stream>>>(
        X, Y, Xb, Yb, yT, y2s, N, M);

    msk_main<<<dim3(N / 128, S), dim3(256), 0, stream>>>(
        Xb, Yb, yT, y2s, pnom, pden, N, M, chunk);

    msk_reduce<<<dim3((N * 32 + 255) / 256), dim3(256), 0, stream>>>(
        pnom, pden, out, N, S);
}

// Round 8
// 93.676 us; speedup vs baseline: 1.0197x; 1.0197x over previous
//
#include <hip/hip_runtime.h>
#include <hip/hip_bf16.h>

#define D 32
#define FACTOR (-1.0f / 128.0f)   // -1/(2*8^2)
#define LOG2E  1.44269504088896340736f

typedef __attribute__((ext_vector_type(8)))  short bf16x8;
typedef __attribute__((ext_vector_type(16))) float f32x16;
typedef __attribute__((ext_vector_type(4)))  float f32x4;

#if __has_builtin(__builtin_amdgcn_exp2f)
#define EXP2(x) __builtin_amdgcn_exp2f(x)
#else
#define EXP2(x) exp2f(x)
#endif

__device__ __forceinline__ ushort bfr(float x) {
    __hip_bfloat16 h = __float2bfloat16(x);     // RNE
    return *reinterpret_cast<ushort*>(&h);
}
__device__ __forceinline__ float bf2f(ushort u) {
    uint w = ((uint)u) << 16;
    return *reinterpret_cast<float*>(&w);
}
__device__ __forceinline__ uint pk2(float a, float b) {
    return (uint)bfr(a) | ((uint)bfr(b) << 16);
}

// ---------------------------------------------------------------------------
// Prep: bf16 copies of X and Y, transposed yT[d][m], and y2s[m] =
// (FACTOR*LOG2E) * ||y~_m||^2. The x^2 term cancels in nom/den and is
// dropped. 4 lanes per row, 8 elements per lane.
// ---------------------------------------------------------------------------
__global__ __launch_bounds__(256) void msk_prep(const float* __restrict__ X,
                                                const float* __restrict__ Y,
                                                ushort* __restrict__ Xb,
                                                ushort* __restrict__ Yb,
                                                ushort* __restrict__ yT,
                                                float* __restrict__ y2s,
                                                int N, int M) {
    const int t = blockIdx.x * 256 + threadIdx.x;
    const int i = t >> 2;
    const int c = t & 3;
    if (i >= N + M) return;
    const bool isX = (i < N);
    const int r = isX ? i : i - N;
    const float* src = (isX ? X : Y) + (size_t)r * D + c * 8;

    float4 va = *reinterpret_cast<const float4*>(src);
    float4 vb = *reinterpret_cast<const float4*>(src + 4);
    float f[8] = {va.x, va.y, va.z, va.w, vb.x, vb.y, vb.z, vb.w};

    ushort u[8];
    float s = 0.f;
#pragma unroll
    for (int k = 0; k < 8; ++k) {
        u[k] = bfr(f[k]);
        float g = bf2f(u[k]);
        s = fmaf(g, g, s);
    }
    s += __shfl_xor(s, 1);
    s += __shfl_xor(s, 2);

    uint w[4];
#pragma unroll
    for (int q = 0; q < 4; ++q) w[q] = (uint)u[2 * q] | ((uint)u[2 * q + 1] << 16);

    ushort* dstrow = (isX ? Xb : Yb) + (size_t)r * D + c * 8;
    *reinterpret_cast<uint4*>(dstrow) = *reinterpret_cast<const uint4*>(w);

    if (!isX) {
        if (c == 0) y2s[r] = s * (FACTOR * LOG2E);
#pragma unroll
        for (int k = 0; k < 8; ++k)
            yT[(size_t)(c * 8 + k) * M + r] = u[k];
    }
}

// ---------------------------------------------------------------------------
// Main fused kernel, phase-split for cross-tile ILP.
// Block = 4 waves x 32 n = 128 n sharing the m-stream. Per 128-m step:
//   Phase A: ALL 8 A-frag ds_reads + ALL 8 GEMM1 MFMAs (4 indep chains)
//   (staging of t+1 + global prefetch of t+2 issued here, after A's reads)
//   Phase B: ALL 64 exp2/pack ops (every s-tile already retired)
//   Phase C: ALL 32 B-frag ds_reads + 8 GEMM2 MFMAs into nom
// One barrier per step. k' = exp2(dot*C2 + y2s[m]) (x^2 cancels).
// ---------------------------------------------------------------------------
__global__ __launch_bounds__(256) void msk_main(const ushort* __restrict__ Xb,
                                                const ushort* __restrict__ Yb,
                                                const ushort* __restrict__ yT,
                                                const float* __restrict__ y2s,
                                                float* __restrict__ pnom,
                                                float* __restrict__ pden,
                                                int N, int M, int chunk) {
    __shared__ uint4 lYb[2][128][4];   // [buf][m-row][16B slot], slot c at c^(r&3)
    __shared__ uint4 lYT[2][32][16];   // [buf][d-row][16B slot], slot s at s^(d&7)

    const int tid  = threadIdx.x;
    const int lane = tid & 63;
    const int wid  = tid >> 6;
    const int h    = lane >> 5;
    const int ln   = lane & 31;
    const int n0   = blockIdx.x * 128 + wid * 32;
    const int m0b  = blockIdx.y * chunk;
    const int ns   = chunk >> 7;                 // 128-m steps

    const int rY = tid >> 2, cY = tid & 3;       // Yb tile roles
    const int dT = tid >> 3, sT = tid & 7;       // yT tile roles

    // x B-fragments: element (h,j) <-> d = 16*ks + 8h + j
    const ushort* xrow = Xb + (size_t)(n0 + ln) * D + h * 8;
    const bf16x8 xf0 = *reinterpret_cast<const bf16x8*>(xrow);
    const bf16x8 xf1 = *reinterpret_cast<const bf16x8*>(xrow + 16);

    const float C2 = -2.0f * (FACTOR * LOG2E);

    f32x16 nom = {};
    float den0 = 0.f, den1 = 0.f;
    union Fu { uint u[4]; bf16x8 v; };

    uint4 ldY0, ldY1, ldT0, ldT1;
    auto issue_loads = [&](int step) {
        const int m = m0b + step * 128;
        ldY0 = (reinterpret_cast<const uint4*>(Yb + (size_t)(m + rY) * D))[cY];
        ldY1 = (reinterpret_cast<const uint4*>(Yb + (size_t)(m + rY + 64) * D))[cY];
        const uint4* tp = reinterpret_cast<const uint4*>(yT + (size_t)dT * M + m);
        ldT0 = tp[sT];
        ldT1 = tp[sT + 8];
    };
    auto stage = [&](int bb) {
        lYb[bb][rY][cY ^ (rY & 3)]       = ldY0;
        lYb[bb][rY + 64][cY ^ (rY & 3)]  = ldY1;
        lYT[bb][dT][sT ^ (dT & 7)]       = ldT0;
        lYT[bb][dT][(sT + 8) ^ (dT & 7)] = ldT1;
    };

    issue_loads(0);
    stage(0);
    if (ns > 1) issue_loads(1);
    __syncthreads();

    const int swA = ln & 3;
    const int sw  = ln & 7;

    for (int t = 0; t < ns; ++t) {
        const int b  = t & 1;
        const int m0 = m0b + t * 128;

        // ---------------- Phase A: all A-frag reads + all GEMM1 MFMAs
        const bf16x8 a00 = *reinterpret_cast<const bf16x8*>(&lYb[b][ 0 + ln][(0 + h) ^ swA]);
        const bf16x8 a01 = *reinterpret_cast<const bf16x8*>(&lYb[b][ 0 + ln][(2 + h) ^ swA]);
        const bf16x8 a10 = *reinterpret_cast<const bf16x8*>(&lYb[b][32 + ln][(0 + h) ^ swA]);
        const bf16x8 a11 = *reinterpret_cast<const bf16x8*>(&lYb[b][32 + ln][(2 + h) ^ swA]);
        const bf16x8 a20 = *reinterpret_cast<const bf16x8*>(&lYb[b][64 + ln][(0 + h) ^ swA]);
        const bf16x8 a21 = *reinterpret_cast<const bf16x8*>(&lYb[b][64 + ln][(2 + h) ^ swA]);
        const bf16x8 a30 = *reinterpret_cast<const bf16x8*>(&lYb[b][96 + ln][(0 + h) ^ swA]);
        const bf16x8 a31 = *reinterpret_cast<const bf16x8*>(&lYb[b][96 + ln][(2 + h) ^ swA]);

        f32x16 s0 = {}, s1 = {}, s2 = {}, s3 = {};
        s0 = __builtin_amdgcn_mfma_f32_32x32x16_bf16(a00, xf0, s0, 0, 0, 0);
        s1 = __builtin_amdgcn_mfma_f32_32x32x16_bf16(a10, xf0, s1, 0, 0, 0);
        s2 = __builtin_amdgcn_mfma_f32_32x32x16_bf16(a20, xf0, s2, 0, 0, 0);
        s3 = __builtin_amdgcn_mfma_f32_32x32x16_bf16(a30, xf0, s3, 0, 0, 0);
        s0 = __builtin_amdgcn_mfma_f32_32x32x16_bf16(a01, xf1, s0, 0, 0, 0);
        s1 = __builtin_amdgcn_mfma_f32_32x32x16_bf16(a11, xf1, s1, 0, 0, 0);
        s2 = __builtin_amdgcn_mfma_f32_32x32x16_bf16(a21, xf1, s2, 0, 0, 0);
        s3 = __builtin_amdgcn_mfma_f32_32x32x16_bf16(a31, xf1, s3, 0, 0, 0);
        // s reg r: m = m0 + tile*32 + (r&3) + 8*(r>>2) + 4h ; n = n0 + ln

        // ---------------- staging for t+1 / prefetch t+2 (covers MFMA latency)
        if (t + 1 < ns) {
            stage((t + 1) & 1);
            if (t + 2 < ns) issue_loads(t + 2);
        }

        // ---------------- Phase B: all exp/pack (s-tiles retired by now)
        Fu pa00, pa01, pa10, pa11, pa20, pa21, pa30, pa31;
#define EXPACK(SV, MT, PA0, PA1)                                                  \
        {                                                                         \
            _Pragma("unroll")                                                     \
            for (int r4 = 0; r4 < 4; ++r4) {                                      \
                f32x4 yv = *reinterpret_cast<const f32x4*>(y2s + (MT) + r4 * 8 + h * 4); \
                float k0 = EXP2(fmaf(SV[r4 * 4 + 0], C2, yv[0]));                 \
                float k1 = EXP2(fmaf(SV[r4 * 4 + 1], C2, yv[1]));                 \
                float k2 = EXP2(fmaf(SV[r4 * 4 + 2], C2, yv[2]));                 \
                float k3 = EXP2(fmaf(SV[r4 * 4 + 3], C2, yv[3]));                 \
                den0 += k0 + k1;                                                  \
                den1 += k2 + k3;                                                  \
                uint w0 = pk2(k0, k1);                                            \
                uint w1 = pk2(k2, k3);                                            \
                if (r4 < 2) { PA0.u[r4 * 2] = w0; PA0.u[r4 * 2 + 1] = w1; }       \
                else        { PA1.u[(r4 - 2) * 2] = w0; PA1.u[(r4 - 2) * 2 + 1] = w1; } \
            }                                                                     \
        }
        EXPACK(s0, m0 +  0, pa00, pa01)
        EXPACK(s1, m0 + 32, pa10, pa11)
        EXPACK(s2, m0 + 64, pa20, pa21)
        EXPACK(s3, m0 + 96, pa30, pa31)
#undef EXPACK

        // ---------------- Phase C: all B-frag reads + all GEMM2 MFMAs
        const uint2* yr = reinterpret_cast<const uint2*>(&lYT[b][ln][0]);
        Fu b00, b01, b10, b11, b20, b21, b30, b31;
#define LDB(BF, Q0, Q1)                                                           \
        *reinterpret_cast<uint2*>(&BF.u[0]) = yr[((Q0) ^ sw) * 2 + h];            \
        *reinterpret_cast<uint2*>(&BF.u[2]) = yr[((Q1) ^ sw) * 2 + h];
        LDB(b00,  0,  1) LDB(b01,  2,  3)
        LDB(b10,  4,  5) LDB(b11,  6,  7)
        LDB(b20,  8,  9) LDB(b21, 10, 11)
        LDB(b30, 12, 13) LDB(b31, 14, 15)
#undef LDB

        nom = __builtin_amdgcn_mfma_f32_32x32x16_bf16(pa00.v, b00.v, nom, 0, 0, 0);
        nom = __builtin_amdgcn_mfma_f32_32x32x16_bf16(pa01.v, b01.v, nom, 0, 0, 0);
        nom = __builtin_amdgcn_mfma_f32_32x32x16_bf16(pa10.v, b10.v, nom, 0, 0, 0);
        nom = __builtin_amdgcn_mfma_f32_32x32x16_bf16(pa11.v, b11.v, nom, 0, 0, 0);
        nom = __builtin_amdgcn_mfma_f32_32x32x16_bf16(pa20.v, b20.v, nom, 0, 0, 0);
        nom = __builtin_amdgcn_mfma_f32_32x32x16_bf16(pa21.v, b21.v, nom, 0, 0, 0);
        nom = __builtin_amdgcn_mfma_f32_32x32x16_bf16(pa30.v, b30.v, nom, 0, 0, 0);
        nom = __builtin_amdgcn_mfma_f32_32x32x16_bf16(pa31.v, b31.v, nom, 0, 0, 0);

        __syncthreads();
    }

    // den: halves hold disjoint m partials for the same n=ln
    float den = den0 + den1;
    den += __shfl_xor(den, 32);

    const size_t base = (size_t)blockIdx.y * N;
#pragma unroll
    for (int r = 0; r < 16; ++r) {
        const int row = (r & 3) + 8 * (r >> 2) + 4 * h;      // n offset
        pnom[(base + n0 + row) * 32 + ln] = nom[r];          // d = ln
    }
    if (h == 0) pden[base + n0 + ln] = den;
}

// ---------------------------------------------------------------------------
// Reduce over m-chunks and divide.
// ---------------------------------------------------------------------------
__global__ __launch_bounds__(256) void msk_reduce(const float* __restrict__ pnom,
                                                  const float* __restrict__ pden,
                                                  float* __restrict__ out,
                                                  int N, int S) {
    const int t = blockIdx.x * blockDim.x + threadIdx.x;
    if (t >= N * 32) return;
    const int n = t >> 5;
    float nom = 0.f, den = 0.f;
    for (int s = 0; s < S; ++s) {
        nom += pnom[(size_t)s * N * 32 + t];
        den += pden[(size_t)s * N + n];
    }
    out[t] = nom / den;
}

// ---------------------------------------------------------------------------
extern "C" void kernel_launch(void* const* d_in, const int* in_sizes, int n_in,
                              void* d_out, int out_size, void* d_ws, size_t ws_size,
                              hipStream_t stream) {
    const float* X = (const float*)d_in[0];
    const float* Y = (const float*)d_in[1];
    float* out     = (float*)d_out;

    const int N = in_sizes[0] / D;   // 8192
    const int M = in_sizes[1] / D;   // 8192

    char* p = (char*)d_ws;
    ushort* Xb  = (ushort*)p; p += (size_t)N * D * sizeof(ushort);
    ushort* Yb  = (ushort*)p; p += (size_t)M * D * sizeof(ushort);
    ushort* yT  = (ushort*)p; p += (size_t)M * D * sizeof(ushort);
    float*  y2s = (float*)p;  p += (size_t)M * sizeof(float);
    size_t used = (size_t)(p - (char*)d_ws);
    used = (used + 255) & ~(size_t)255;

    const size_t per_s = (size_t)N * 33 * sizeof(float);
    int S = 16;                                  // 1024 blocks
    while (S > 1 && used + (size_t)S * per_s > ws_size) S >>= 1;
    const int chunk = M / S;                     // 512 -> 4 steps of 128 m

    float* pnom = (float*)((char*)d_ws + used);
    float* pden = pnom + (size_t)S * N * 32;

    msk_prep<<<dim3(((N + M) * 4 + 255) / 256), dim3(256), 0, stream>>>(
        X, Y, Xb, Yb, yT, y2s, N, M);

    msk_main<<<dim3(N / 128, S), dim3(256), 0, stream>>>(
        Xb, Yb, yT, y2s, pnom, pden, N, M, chunk);

    msk_reduce<<<dim3((N * 32 + 255) / 256), dim3(256), 0, stream>>>(
        pnom, pden, out, N, S);
}